// Round 1
// baseline (35633.057 us; speedup 1.0000x reference)
//
#include <hip/hip_runtime.h>
#include <math.h>

// FWI forward modeling: 10 shots, 1000 timesteps, padded grid 130x160 (NBC=30).
// One block per shot; field p1 in LDS with zero halo; p0/p_new in registers.
// Zero BC replaces jnp.roll wraparound (contribution < 1e-7 rel through 2x
// absorbing-layer traversal).

#define NZg 130
#define NXg 160
#define SROW 164                 // stored row stride: 2 halo + 160 + 2 halo
#define LDSZ (134 * SROW)        // 134 rows (2 halo + 130 + 2 halo) = 21976 floats
#define DTf 0.0008f
#define C2f 1.3333333333333333f  // 4/3
#define C3f (-0.08333333333333333f) // -1/12

// ---------- setup 1: velmin reduction, Ricker wavelet, source amplitudes ----------
__global__ __launch_bounds__(1024) void fwi_setup1(const float* __restrict__ v,
                                                   float* __restrict__ ws) {
    int tid = threadIdx.x;
    // min over 70x100 interior v
    float m = 3.402823466e38f;
    for (int i = tid; i < 7000; i += 1024) m = fminf(m, v[i]);
    #pragma unroll
    for (int off = 32; off > 0; off >>= 1) m = fminf(m, __shfl_down(m, off, 64));
    __shared__ float red[16];
    if ((tid & 63) == 0) red[tid >> 6] = m;
    __syncthreads();
    if (tid == 0) {
        float mm = red[0];
        for (int i = 1; i < 16; ++i) mm = fminf(mm, red[i]);
        ws[1010] = mm * 1000.0f + 3000.0f;   // denormalized velmin
    }
    // Ricker wavelet: nw=111, nc=55, f*dt*pi = 0.06283185307179587
    if (tid < 1000) {
        float w = 0.0f;
        if (tid < 111) {
            float a = (float)(55 - tid) * 0.06283185307179587f;
            float b = a * a;
            w = (1.0f - 2.0f * b) * expf(-b);
        }
        ws[tid] = w;
    }
    // src_amp[l] = ((v[1][11l]*1000+3000)*DT)^2
    if (tid >= 1000 && tid < 1010) {
        int l = tid - 1000;
        float vd = v[100 + 11 * l] * 1000.0f + 3000.0f;
        float bdt = vd * DTf;
        ws[tid] = bdt * bdt;
    }
}

// ---------- setup 2: per-cell constants {alpha, temp1} ----------
__global__ __launch_bounds__(256) void fwi_setup2(const float* __restrict__ v,
                                                  const float* __restrict__ ws,
                                                  float2* __restrict__ cst) {
    int c = blockIdx.x * 256 + threadIdx.x;
    if (c >= NZg * NXg) return;
    float velmin = ws[1010];
    int z = c / NXg;
    int x = c - z * NXg;
    // edge padding: clamp into 70x100 interior
    int iz = min(max(z - 30, 0), 69);
    int ix = min(max(x - 30, 0), 99);
    float vd = v[iz * 100 + ix] * 1000.0f + 3000.0f;
    float tt = vd * DTf / 10.0f;       // v*DT/DX
    float al = tt * tt;                // alpha
    // absorbing profile index: x-bands override z-bands (matches reference .set order)
    int qx = max(29 - x, x - 130);
    int qz = max(29 - z, z - 100);
    int q = (qx >= 0) ? qx : qz;
    float kdt = 0.0f;
    if (q >= 0) {
        float kap3 = 3.0f * velmin * 16.118095650958319f / 580.0f; // 3*velmin*ln(1e7)/(2*290)
        float r = (float)q * (10.0f / 290.0f);
        kdt = kap3 * (r * r) * DTf;
    }
    float t1 = 2.0f - 5.0f * al - kdt;  // 2 + 2*C1*alpha - kappa*DT, C1=-2.5
    cst[c] = make_float2(al, t1);       // t2 = 1-kdt = t1 + 5*al - 1 (derived in main)
}

// ---------- main: one block per shot, 1000 steps ----------
__global__ __launch_bounds__(512) void fwi_main(const float4* __restrict__ cst4,
                                                const float* __restrict__ ws,
                                                float* __restrict__ out) {
    __shared__ float Ps[LDSZ];   // 87,904 B: p1 with zero halo
    const int tid = threadIdx.x;
    const int shot = blockIdx.x;

    // zero the whole buffer (field init + permanent zero halo)
    for (int i = tid; i < LDSZ; i += 512) Ps[i] = 0.0f;

    // each thread owns 21 x-adjacent cell PAIRS: pair P = k*512 + tid, cells 2P,2P+1
    // 10400 pairs total = 512*20 + 160 (k==20 valid only for tid<160)
    int addr[21];
    float p00[21], p01[21], pn0[21], pn1[21];
    #pragma unroll
    for (int k = 0; k < 21; ++k) {
        int P = (k << 9) + tid;
        int z = P / 80;                  // 80 pairs per row, pairs never straddle rows
        addr[k] = 2 * P + 4 * z + 330;   // (z+2)*164 + (x0+2)
        p00[k] = 0.0f; p01[k] = 0.0f;
    }
    const float amp = ws[1000 + shot];
    const int csrc = 4990 + 11 * shot;   // 31*160 + (30+11*shot)
    const int tid2 = tid * 2;
    const bool last = (tid < 160);
    const int outbase = shot * 100000 + tid;
    __syncthreads();

    for (int t = 0; t < 1000; ++t) {
        float as = amp * ws[t];
        // phase A: stencil from LDS p1, p_new -> regs, p0 <- p1(center)
        #pragma unroll
        for (int k = 0; k < 21; ++k) {
            if (k < 20 || last) {
                const int a = addr[k];
                __builtin_assume((a & 1) == 0);      // enables b64/read2 merging
                float c0  = Ps[a],          c1  = Ps[a + 1];
                float l2  = Ps[a - 2],      l1  = Ps[a - 1];
                float r1  = Ps[a + 2],      r2  = Ps[a + 3];
                float u10 = Ps[a - SROW],   u11 = Ps[a - SROW + 1];
                float d10 = Ps[a + SROW],   d11 = Ps[a + SROW + 1];
                float u20 = Ps[a - 2*SROW], u21 = Ps[a - 2*SROW + 1];
                float d20 = Ps[a + 2*SROW], d21 = Ps[a + 2*SROW + 1];
                float4 ct = cst4[(k << 9) + tid];    // {al0,t1_0, al1,t1_1}
                float lap0 = C2f * ((l1 + c1) + (u10 + d10)) + C3f * ((l2 + r1) + (u20 + d20));
                float lap1 = C2f * ((c0 + r1) + (u11 + d11)) + C3f * ((l1 + r2) + (u21 + d21));
                float t20 = ct.y + 5.0f * ct.x - 1.0f;   // temp2 = 1 - kdt
                float t21 = ct.w + 5.0f * ct.z - 1.0f;
                float q0 = ct.y * c0 - t20 * p00[k] + ct.x * lap0;
                float q1 = ct.w * c1 - t21 * p01[k] + ct.z * lap1;
                int ci = (k << 10) + tid2;               // global cell index of cell0
                if (ci == csrc)     q0 += as;            // source injection (post-stencil)
                if (ci + 1 == csrc) q1 += as;
                pn0[k] = q0; pn1[k] = q1;
                p00[k] = c0; p01[k] = c1;
            }
        }
        __syncthreads();
        // phase B: write p_new into LDS
        #pragma unroll
        for (int k = 0; k < 21; ++k) {
            if (k < 20 || last) {
                const int a = addr[k];
                __builtin_assume((a & 1) == 0);
                Ps[a] = pn0[k];
                Ps[a + 1] = pn1[k];
            }
        }
        __syncthreads();
        // phase C: receivers at z=31 (stored row 33), x=30..129 (stored col 32..131)
        if (tid < 100) out[outbase + t * 100] = Ps[33 * SROW + 32 + tid];
        // no barrier needed: next phase A only reads; next writes are after next barrier
    }
}

extern "C" void kernel_launch(void* const* d_in, const int* in_sizes, int n_in,
                              void* d_out, int out_size, void* d_ws, size_t ws_size,
                              hipStream_t stream) {
    const float* v = (const float*)d_in[0];
    float* ws = (float*)d_ws;                       // [0..999] wavelet, [1000..1009] amps, [1010] velmin
    float2* cst = (float2*)((char*)d_ws + 4096);    // 20800 x {alpha, temp1}
    float* out = (float*)d_out;

    fwi_setup1<<<1, 1024, 0, stream>>>(v, ws);
    fwi_setup2<<<82, 256, 0, stream>>>(v, ws, cst);
    fwi_main<<<10, 512, 0, stream>>>((const float4*)cst, ws, out);
}

// Round 2
// 35628.439 us; speedup vs baseline: 1.0001x; 1.0001x over previous
//
#include <hip/hip_runtime.h>
#include <math.h>

// FWI forward modeling: 10 shots, 1000 timesteps, padded grid 130x160 (NBC=30).
// One block per shot; field p1 in LDS with zero halo; p0/p_new in registers.
// Zero BC replaces jnp.roll wraparound (contribution < 1e-7 rel through 2x
// absorbing-layer traversal).
//
// R2 change: __launch_bounds__(512, 2) -> 256-VGPR cap. R1's (512) defaulted
// to a 128-VGPR budget and spilled the 105-element per-thread state to
// scratch, latency-serializing every LDS/global load (35 us/step).

#define NZg 130
#define NXg 160
#define SROW 164                 // stored row stride: 2 halo + 160 + 2 halo
#define LDSZ (134 * SROW)        // 134 rows (2 halo + 130 + 2 halo) = 21976 floats
#define DTf 0.0008f
#define C2f 1.3333333333333333f  // 4/3
#define C3f (-0.08333333333333333f) // -1/12

// ---------- setup 1: velmin reduction, Ricker wavelet, source amplitudes ----------
__global__ __launch_bounds__(1024) void fwi_setup1(const float* __restrict__ v,
                                                   float* __restrict__ ws) {
    int tid = threadIdx.x;
    // min over 70x100 interior v
    float m = 3.402823466e38f;
    for (int i = tid; i < 7000; i += 1024) m = fminf(m, v[i]);
    #pragma unroll
    for (int off = 32; off > 0; off >>= 1) m = fminf(m, __shfl_down(m, off, 64));
    __shared__ float red[16];
    if ((tid & 63) == 0) red[tid >> 6] = m;
    __syncthreads();
    if (tid == 0) {
        float mm = red[0];
        for (int i = 1; i < 16; ++i) mm = fminf(mm, red[i]);
        ws[1010] = mm * 1000.0f + 3000.0f;   // denormalized velmin
    }
    // Ricker wavelet: nw=111, nc=55, f*dt*pi = 0.06283185307179587
    if (tid < 1000) {
        float w = 0.0f;
        if (tid < 111) {
            float a = (float)(55 - tid) * 0.06283185307179587f;
            float b = a * a;
            w = (1.0f - 2.0f * b) * expf(-b);
        }
        ws[tid] = w;
    }
    // src_amp[l] = ((v[1][11l]*1000+3000)*DT)^2
    if (tid >= 1000 && tid < 1010) {
        int l = tid - 1000;
        float vd = v[100 + 11 * l] * 1000.0f + 3000.0f;
        float bdt = vd * DTf;
        ws[tid] = bdt * bdt;
    }
}

// ---------- setup 2: per-cell constants {alpha, temp1} ----------
__global__ __launch_bounds__(256) void fwi_setup2(const float* __restrict__ v,
                                                  const float* __restrict__ ws,
                                                  float2* __restrict__ cst) {
    int c = blockIdx.x * 256 + threadIdx.x;
    if (c >= NZg * NXg) return;
    float velmin = ws[1010];
    int z = c / NXg;
    int x = c - z * NXg;
    // edge padding: clamp into 70x100 interior
    int iz = min(max(z - 30, 0), 69);
    int ix = min(max(x - 30, 0), 99);
    float vd = v[iz * 100 + ix] * 1000.0f + 3000.0f;
    float tt = vd * DTf / 10.0f;       // v*DT/DX
    float al = tt * tt;                // alpha
    // absorbing profile index: x-bands override z-bands (matches reference .set order)
    int qx = max(29 - x, x - 130);
    int qz = max(29 - z, z - 100);
    int q = (qx >= 0) ? qx : qz;
    float kdt = 0.0f;
    if (q >= 0) {
        float kap3 = 3.0f * velmin * 16.118095650958319f / 580.0f; // 3*velmin*ln(1e7)/(2*290)
        float r = (float)q * (10.0f / 290.0f);
        kdt = kap3 * (r * r) * DTf;
    }
    float t1 = 2.0f - 5.0f * al - kdt;  // 2 + 2*C1*alpha - kappa*DT, C1=-2.5
    cst[c] = make_float2(al, t1);       // t2 = 1-kdt = t1 + 5*al - 1 (derived in main)
}

// ---------- main: one block per shot, 1000 steps ----------
__global__ __launch_bounds__(512, 2) void fwi_main(const float4* __restrict__ cst4,
                                                   const float* __restrict__ ws,
                                                   float* __restrict__ out) {
    __shared__ float Ps[LDSZ];   // 87,904 B: p1 with zero halo
    const int tid = threadIdx.x;
    const int shot = blockIdx.x;

    // zero the whole buffer (field init + permanent zero halo)
    for (int i = tid; i < LDSZ; i += 512) Ps[i] = 0.0f;

    // each thread owns 21 x-adjacent cell PAIRS: pair P = k*512 + tid, cells 2P,2P+1
    // 10400 pairs total = 512*20 + 160 (k==20 valid only for tid<160)
    int addr[21];
    float p00[21], p01[21], pn0[21], pn1[21];
    #pragma unroll
    for (int k = 0; k < 21; ++k) {
        int P = (k << 9) + tid;
        int z = P / 80;                  // 80 pairs per row, pairs never straddle rows
        addr[k] = 2 * P + 4 * z + 330;   // (z+2)*164 + (x0+2)
        p00[k] = 0.0f; p01[k] = 0.0f;
    }
    const float amp = ws[1000 + shot];
    const int csrc = 4990 + 11 * shot;   // 31*160 + (30+11*shot)
    const int tid2 = tid * 2;
    const bool last = (tid < 160);
    const int outbase = shot * 100000 + tid;
    __syncthreads();

    for (int t = 0; t < 1000; ++t) {
        float as = amp * ws[t];
        // phase A: stencil from LDS p1, p_new -> regs, p0 <- p1(center)
        #pragma unroll
        for (int k = 0; k < 21; ++k) {
            if (k < 20 || last) {
                const int a = addr[k];
                __builtin_assume((a & 1) == 0);      // enables b64/read2 merging
                float c0  = Ps[a],          c1  = Ps[a + 1];
                float l2  = Ps[a - 2],      l1  = Ps[a - 1];
                float r1  = Ps[a + 2],      r2  = Ps[a + 3];
                float u10 = Ps[a - SROW],   u11 = Ps[a - SROW + 1];
                float d10 = Ps[a + SROW],   d11 = Ps[a + SROW + 1];
                float u20 = Ps[a - 2*SROW], u21 = Ps[a - 2*SROW + 1];
                float d20 = Ps[a + 2*SROW], d21 = Ps[a + 2*SROW + 1];
                float4 ct = cst4[(k << 9) + tid];    // {al0,t1_0, al1,t1_1}
                float lap0 = C2f * ((l1 + c1) + (u10 + d10)) + C3f * ((l2 + r1) + (u20 + d20));
                float lap1 = C2f * ((c0 + r1) + (u11 + d11)) + C3f * ((l1 + r2) + (u21 + d21));
                float t20 = ct.y + 5.0f * ct.x - 1.0f;   // temp2 = 1 - kdt
                float t21 = ct.w + 5.0f * ct.z - 1.0f;
                float q0 = ct.y * c0 - t20 * p00[k] + ct.x * lap0;
                float q1 = ct.w * c1 - t21 * p01[k] + ct.z * lap1;
                int ci = (k << 10) + tid2;               // global cell index of cell0
                if (ci == csrc)     q0 += as;            // source injection (post-stencil)
                if (ci + 1 == csrc) q1 += as;
                pn0[k] = q0; pn1[k] = q1;
                p00[k] = c0; p01[k] = c1;
            }
        }
        __syncthreads();
        // phase B: write p_new into LDS
        #pragma unroll
        for (int k = 0; k < 21; ++k) {
            if (k < 20 || last) {
                const int a = addr[k];
                __builtin_assume((a & 1) == 0);
                Ps[a] = pn0[k];
                Ps[a + 1] = pn1[k];
            }
        }
        __syncthreads();
        // phase C: receivers at z=31 (stored row 33), x=30..129 (stored col 32..131)
        if (tid < 100) out[outbase + t * 100] = Ps[33 * SROW + 32 + tid];
        // no barrier needed: next phase A only reads; next writes are after next barrier
    }
}

extern "C" void kernel_launch(void* const* d_in, const int* in_sizes, int n_in,
                              void* d_out, int out_size, void* d_ws, size_t ws_size,
                              hipStream_t stream) {
    const float* v = (const float*)d_in[0];
    float* ws = (float*)d_ws;                       // [0..999] wavelet, [1000..1009] amps, [1010] velmin
    float2* cst = (float2*)((char*)d_ws + 4096);    // 20800 x {alpha, temp1}
    float* out = (float*)d_out;

    fwi_setup1<<<1, 1024, 0, stream>>>(v, ws);
    fwi_setup2<<<82, 256, 0, stream>>>(v, ws, cst);
    fwi_main<<<10, 512, 0, stream>>>((const float4*)cst, ws, out);
}

// Round 3
// 34890.045 us; speedup vs baseline: 1.0213x; 1.0212x over previous
//
#include <hip/hip_runtime.h>
#include <math.h>

// FWI forward modeling: 10 shots, 1000 timesteps, padded grid 130x160 (NBC=30).
// One block per shot; field p1 in LDS with zero halo; p0/p_new in registers.
// Zero BC replaces jnp.roll wraparound (contribution < 1e-7 rel through 2x
// absorbing-layer traversal).
//
// R3 changes:
//  - amdgpu_waves_per_eu(2,2): R2's launch_bounds(512,2) only set MIN waves
//    (VGPR cap), and the allocator still targeted 4 waves/EU = 128 VGPRs,
//    spilling the ~105-reg per-thread state. Pinning min=max=2 tells the
//    allocator exactly what LDS (88KB -> 1 block/CU) already implies, so it
//    can use 256 VGPRs.
//  - hoist time-invariant cst4 coefficient loads (21 x float4) out of the
//    1000-step loop into persistent registers; Ricker wavelet into LDS.
//    Steady-state loop is pure LDS+VALU.

#define NZg 130
#define NXg 160
#define SROW 164                 // stored row stride: 2 halo + 160 + 2 halo
#define LDSZ (134 * SROW)        // 134 rows (2 halo + 130 + 2 halo) = 21976 floats
#define DTf 0.0008f
#define C2f 1.3333333333333333f  // 4/3
#define C3f (-0.08333333333333333f) // -1/12

// ---------- setup 1: velmin reduction, Ricker wavelet, source amplitudes ----------
__global__ __launch_bounds__(1024) void fwi_setup1(const float* __restrict__ v,
                                                   float* __restrict__ ws) {
    int tid = threadIdx.x;
    // min over 70x100 interior v
    float m = 3.402823466e38f;
    for (int i = tid; i < 7000; i += 1024) m = fminf(m, v[i]);
    #pragma unroll
    for (int off = 32; off > 0; off >>= 1) m = fminf(m, __shfl_down(m, off, 64));
    __shared__ float red[16];
    if ((tid & 63) == 0) red[tid >> 6] = m;
    __syncthreads();
    if (tid == 0) {
        float mm = red[0];
        for (int i = 1; i < 16; ++i) mm = fminf(mm, red[i]);
        ws[1010] = mm * 1000.0f + 3000.0f;   // denormalized velmin
    }
    // Ricker wavelet: nw=111, nc=55, f*dt*pi = 0.06283185307179587
    if (tid < 1000) {
        float w = 0.0f;
        if (tid < 111) {
            float a = (float)(55 - tid) * 0.06283185307179587f;
            float b = a * a;
            w = (1.0f - 2.0f * b) * expf(-b);
        }
        ws[tid] = w;
    }
    // src_amp[l] = ((v[1][11l]*1000+3000)*DT)^2
    if (tid >= 1000 && tid < 1010) {
        int l = tid - 1000;
        float vd = v[100 + 11 * l] * 1000.0f + 3000.0f;
        float bdt = vd * DTf;
        ws[tid] = bdt * bdt;
    }
}

// ---------- setup 2: per-cell constants {alpha, temp1} ----------
__global__ __launch_bounds__(256) void fwi_setup2(const float* __restrict__ v,
                                                  const float* __restrict__ ws,
                                                  float2* __restrict__ cst) {
    int c = blockIdx.x * 256 + threadIdx.x;
    if (c >= NZg * NXg) return;
    float velmin = ws[1010];
    int z = c / NXg;
    int x = c - z * NXg;
    // edge padding: clamp into 70x100 interior
    int iz = min(max(z - 30, 0), 69);
    int ix = min(max(x - 30, 0), 99);
    float vd = v[iz * 100 + ix] * 1000.0f + 3000.0f;
    float tt = vd * DTf / 10.0f;       // v*DT/DX
    float al = tt * tt;                // alpha
    // absorbing profile index: x-bands override z-bands (matches reference .set order)
    int qx = max(29 - x, x - 130);
    int qz = max(29 - z, z - 100);
    int q = (qx >= 0) ? qx : qz;
    float kdt = 0.0f;
    if (q >= 0) {
        float kap3 = 3.0f * velmin * 16.118095650958319f / 580.0f; // 3*velmin*ln(1e7)/(2*290)
        float r = (float)q * (10.0f / 290.0f);
        kdt = kap3 * (r * r) * DTf;
    }
    float t1 = 2.0f - 5.0f * al - kdt;  // 2 + 2*C1*alpha - kappa*DT, C1=-2.5
    cst[c] = make_float2(al, t1);       // t2 = 1-kdt = t1 + 5*al - 1 (derived in main)
}

// ---------- main: one block per shot, 1000 steps ----------
__global__
__attribute__((amdgpu_flat_work_group_size(512, 512), amdgpu_waves_per_eu(2, 2)))
void fwi_main(const float4* __restrict__ cst4,
              const float* __restrict__ ws,
              float* __restrict__ out) {
    __shared__ float Ps[LDSZ];   // 87,904 B: p1 with zero halo
    __shared__ float Wv[1024];   // Ricker wavelet (time-series), LDS-resident
    const int tid = threadIdx.x;
    const int shot = blockIdx.x;

    // zero the whole buffer (field init + permanent zero halo)
    for (int i = tid; i < LDSZ; i += 512) Ps[i] = 0.0f;
    // wavelet -> LDS
    Wv[tid] = ws[tid];
    Wv[tid + 512] = ws[tid + 512];

    // each thread owns 21 x-adjacent cell PAIRS: pair P = k*512 + tid, cells 2P,2P+1
    // 10400 pairs total = 512*20 + 160 (k==20 valid only for tid<160)
    int addr[21];
    float p00[21], p01[21], pn0[21], pn1[21];
    float4 ct[21];               // time-invariant {al0,t1_0,al1,t1_1} per pair
    const bool last = (tid < 160);
    #pragma unroll
    for (int k = 0; k < 21; ++k) {
        int P = (k << 9) + tid;
        int z = P / 80;                  // 80 pairs per row, pairs never straddle rows
        addr[k] = 2 * P + 4 * z + 330;   // (z+2)*164 + (x0+2)
        p00[k] = 0.0f; p01[k] = 0.0f;
        if (k < 20 || last) ct[k] = cst4[P];
    }
    const float amp = ws[1000 + shot];
    const int csrc = 4990 + 11 * shot;   // 31*160 + (30+11*shot)
    const int tid2 = tid * 2;
    const int outbase = shot * 100000 + tid;
    __syncthreads();

    for (int t = 0; t < 1000; ++t) {
        float as = amp * Wv[t];
        // phase A: stencil from LDS p1, p_new -> regs, p0 <- p1(center)
        #pragma unroll
        for (int k = 0; k < 21; ++k) {
            if (k < 20 || last) {
                const int a = addr[k];
                __builtin_assume((a & 1) == 0);      // enables b64/read2 merging
                float c0  = Ps[a],          c1  = Ps[a + 1];
                float l2  = Ps[a - 2],      l1  = Ps[a - 1];
                float r1  = Ps[a + 2],      r2  = Ps[a + 3];
                float u10 = Ps[a - SROW],   u11 = Ps[a - SROW + 1];
                float d10 = Ps[a + SROW],   d11 = Ps[a + SROW + 1];
                float u20 = Ps[a - 2*SROW], u21 = Ps[a - 2*SROW + 1];
                float d20 = Ps[a + 2*SROW], d21 = Ps[a + 2*SROW + 1];
                float lap0 = C2f * ((l1 + c1) + (u10 + d10)) + C3f * ((l2 + r1) + (u20 + d20));
                float lap1 = C2f * ((c0 + r1) + (u11 + d11)) + C3f * ((l1 + r2) + (u21 + d21));
                float t20 = ct[k].y + 5.0f * ct[k].x - 1.0f;   // temp2 = 1 - kdt
                float t21 = ct[k].w + 5.0f * ct[k].z - 1.0f;
                float q0 = ct[k].y * c0 - t20 * p00[k] + ct[k].x * lap0;
                float q1 = ct[k].w * c1 - t21 * p01[k] + ct[k].z * lap1;
                int ci = (k << 10) + tid2;               // global cell index of cell0
                if (ci == csrc)     q0 += as;            // source injection (post-stencil)
                if (ci + 1 == csrc) q1 += as;
                pn0[k] = q0; pn1[k] = q1;
                p00[k] = c0; p01[k] = c1;
            }
        }
        __syncthreads();
        // phase B: write p_new into LDS
        #pragma unroll
        for (int k = 0; k < 21; ++k) {
            if (k < 20 || last) {
                const int a = addr[k];
                __builtin_assume((a & 1) == 0);
                Ps[a] = pn0[k];
                Ps[a + 1] = pn1[k];
            }
        }
        __syncthreads();
        // phase C: receivers at z=31 (stored row 33), x=30..129 (stored col 32..131)
        if (tid < 100) out[outbase + t * 100] = Ps[33 * SROW + 32 + tid];
        // no barrier needed: next phase A only reads; next writes are after next barrier
    }
}

extern "C" void kernel_launch(void* const* d_in, const int* in_sizes, int n_in,
                              void* d_out, int out_size, void* d_ws, size_t ws_size,
                              hipStream_t stream) {
    const float* v = (const float*)d_in[0];
    float* ws = (float*)d_ws;                       // [0..999] wavelet, [1000..1009] amps, [1010] velmin
    float2* cst = (float2*)((char*)d_ws + 4096);    // 20800 x {alpha, temp1}
    float* out = (float*)d_out;

    fwi_setup1<<<1, 1024, 0, stream>>>(v, ws);
    fwi_setup2<<<82, 256, 0, stream>>>(v, ws, cst);
    fwi_main<<<10, 512, 0, stream>>>((const float4*)cst, ws, out);
}

// Round 4
// 3648.328 us; speedup vs baseline: 9.7670x; 9.5633x over previous
//
#include <hip/hip_runtime.h>
#include <math.h>

// FWI forward modeling: 10 shots, 1000 timesteps, padded grid 130x160 (NBC=30).
// One block per shot. R4 restructure: the allocator refuses >128 VGPRs
// (R2/R3 attributes had zero effect; identical codegen, spill-bound at
// 35us/step). So make live state fit:
//   - p1 (haloed) in LDS Ps (87.9KB)
//   - p0 in LDS P0s (no halo needed: owner-private) for cells < 17408;
//     last 4 k-slots' p0 in 8 regs/thread. Total LDS 161.5KB <= 160KiB.
//   - p0 updates (old-center copy) happen pre-barrier: owner-private.
//   - only pn[42] + addr[21] persist; ~110 VGPRs total -> no spill.
//   - receivers stored from pn registers (threads 447..496 own row 31).

#define NZg 130
#define NXg 160
#define SROW 164                 // stored row stride: 2 halo + 160 + 2 halo
#define LDSZ (134 * SROW)        // 134 rows (2+130+2) = 21976 floats
#define K_REG 17                 // k >= K_REG: p0 kept in registers
#define P0LDS (8704 * 2)         // p0 cells resident in LDS (pairs 0..8703)
#define DTf 0.0008f
#define C2f 1.3333333333333333f  // 4/3
#define C3f (-0.08333333333333333f) // -1/12

// ---------- setup 1: velmin reduction, Ricker wavelet, source amplitudes ----------
__global__ __launch_bounds__(1024) void fwi_setup1(const float* __restrict__ v,
                                                   float* __restrict__ ws) {
    int tid = threadIdx.x;
    float m = 3.402823466e38f;
    for (int i = tid; i < 7000; i += 1024) m = fminf(m, v[i]);
    #pragma unroll
    for (int off = 32; off > 0; off >>= 1) m = fminf(m, __shfl_down(m, off, 64));
    __shared__ float red[16];
    if ((tid & 63) == 0) red[tid >> 6] = m;
    __syncthreads();
    if (tid == 0) {
        float mm = red[0];
        for (int i = 1; i < 16; ++i) mm = fminf(mm, red[i]);
        ws[1010] = mm * 1000.0f + 3000.0f;   // denormalized velmin
    }
    // Ricker wavelet: nw=111, nc=55, f*dt*pi = 0.06283185307179587
    if (tid < 1000) {
        float w = 0.0f;
        if (tid < 111) {
            float a = (float)(55 - tid) * 0.06283185307179587f;
            float b = a * a;
            w = (1.0f - 2.0f * b) * expf(-b);
        }
        ws[tid] = w;
    }
    // src_amp[l] = ((v[1][11l]*1000+3000)*DT)^2
    if (tid >= 1000 && tid < 1010) {
        int l = tid - 1000;
        float vd = v[100 + 11 * l] * 1000.0f + 3000.0f;
        float bdt = vd * DTf;
        ws[tid] = bdt * bdt;
    }
}

// ---------- setup 2: per-cell constants {alpha, temp1} ----------
__global__ __launch_bounds__(256) void fwi_setup2(const float* __restrict__ v,
                                                  const float* __restrict__ ws,
                                                  float2* __restrict__ cst) {
    int c = blockIdx.x * 256 + threadIdx.x;
    if (c >= NZg * NXg) return;
    float velmin = ws[1010];
    int z = c / NXg;
    int x = c - z * NXg;
    int iz = min(max(z - 30, 0), 69);
    int ix = min(max(x - 30, 0), 99);
    float vd = v[iz * 100 + ix] * 1000.0f + 3000.0f;
    float tt = vd * DTf / 10.0f;       // v*DT/DX
    float al = tt * tt;                // alpha
    int qx = max(29 - x, x - 130);
    int qz = max(29 - z, z - 100);
    int q = (qx >= 0) ? qx : qz;
    float kdt = 0.0f;
    if (q >= 0) {
        float kap3 = 3.0f * velmin * 16.118095650958319f / 580.0f; // 3*velmin*ln(1e7)/(2*290)
        float r = (float)q * (10.0f / 290.0f);
        kdt = kap3 * (r * r) * DTf;
    }
    float t1 = 2.0f - 5.0f * al - kdt;  // 2 + 2*C1*alpha - kappa*DT, C1=-2.5
    cst[c] = make_float2(al, t1);       // t2 = 1-kdt = t1 + 5*al - 1 (derived in main)
}

// ---------- main: one block per shot, 1000 steps ----------
__global__ __launch_bounds__(512) void fwi_main(const float4* __restrict__ cst4,
                                                const float* __restrict__ ws,
                                                float* __restrict__ out) {
    __shared__ float Ps[LDSZ];     // p1 with zero halo (87,904 B)
    __shared__ float P0s[P0LDS];   // p0, plain cell-indexed, cells < 17408 (69,632 B)
    __shared__ float Wv[1000];     // Ricker wavelet (4,000 B)
    const int tid = threadIdx.x;
    const int shot = blockIdx.x;

    for (int i = tid; i < LDSZ; i += 512) Ps[i] = 0.0f;
    for (int i = tid; i < P0LDS; i += 512) P0s[i] = 0.0f;
    if (tid < 1000) Wv[tid] = ws[tid];
    if (tid < 488) Wv[tid + 512] = ws[tid + 512];

    // each thread owns 21 x-adjacent cell PAIRS: pair P = k*512 + tid, cells 2P,2P+1
    // 10400 pairs total = 512*20 + 160 (k==20 valid only for tid<160)
    int addr[21];
    float pn0[21], pn1[21];
    float p0r0[4], p0r1[4];        // p0 for k = 17..20 (owner-private cells)
    #pragma unroll
    for (int k = 0; k < 21; ++k) {
        int P = (k << 9) + tid;
        int z = P / 80;                  // 80 pairs per row; pairs never straddle rows
        addr[k] = 2 * P + 4 * z + 330;   // (z+2)*164 + (x0+2)
    }
    #pragma unroll
    for (int k = 0; k < 4; ++k) { p0r0[k] = 0.0f; p0r1[k] = 0.0f; }
    const float amp = ws[1000 + shot];
    const int csrc = 4990 + 11 * shot;   // 31*160 + (30+11*shot)
    const int tid2 = tid * 2;
    const bool last = (tid < 160);
    __syncthreads();

    for (int t = 0; t < 1000; ++t) {
        float as = amp * Wv[t];
        // phase A: stencil from Ps(p1) + p0; p_new -> pn regs; old center -> p0 store
        #pragma unroll
        for (int k = 0; k < 21; ++k) {
            if (k < 20 || last) {
                const int a = addr[k];
                __builtin_assume((a & 1) == 0);      // b64-merge hint
                float c0  = Ps[a],          c1  = Ps[a + 1];
                float l2  = Ps[a - 2],      l1  = Ps[a - 1];
                float r1  = Ps[a + 2],      r2  = Ps[a + 3];
                float u10 = Ps[a - SROW],   u11 = Ps[a - SROW + 1];
                float d10 = Ps[a + SROW],   d11 = Ps[a + SROW + 1];
                float u20 = Ps[a - 2*SROW], u21 = Ps[a - 2*SROW + 1];
                float d20 = Ps[a + 2*SROW], d21 = Ps[a + 2*SROW + 1];
                const int ci = (k << 10) + tid2;     // global cell index of cell0
                float o0, o1;
                if (k < K_REG) { o0 = P0s[ci]; o1 = P0s[ci + 1]; }
                else           { o0 = p0r0[k - K_REG]; o1 = p0r1[k - K_REG]; }
                float4 ct = cst4[(k << 9) + tid];    // {al0,t1_0, al1,t1_1}
                float lap0 = C2f * ((l1 + c1) + (u10 + d10)) + C3f * ((l2 + r1) + (u20 + d20));
                float lap1 = C2f * ((c0 + r1) + (u11 + d11)) + C3f * ((l1 + r2) + (u21 + d21));
                float t20 = ct.y + 5.0f * ct.x - 1.0f;   // temp2 = 1 - kdt
                float t21 = ct.w + 5.0f * ct.z - 1.0f;
                float q0 = ct.y * c0 - t20 * o0 + ct.x * lap0;
                float q1 = ct.w * c1 - t21 * o1 + ct.z * lap1;
                if (ci == csrc)     q0 += as;            // source injection
                if (ci + 1 == csrc) q1 += as;
                pn0[k] = q0; pn1[k] = q1;
                // p0 <- old p1 center (owner-private: safe before barrier)
                if (k < K_REG) { P0s[ci] = c0; P0s[ci + 1] = c1; }
                else           { p0r0[k - K_REG] = c0; p0r1[k - K_REG] = c1; }
            }
        }
        __syncthreads();             // all 9-pt reads of Ps complete
        // phase B: write p_new into Ps
        #pragma unroll
        for (int k = 0; k < 21; ++k) {
            if (k < 20 || last) {
                const int a = addr[k];
                __builtin_assume((a & 1) == 0);
                Ps[a] = pn0[k];
                Ps[a + 1] = pn1[k];
            }
        }
        // receivers (row z=31, x=30..129 -> cells 4990..5089) live in k=4 regs
        // of threads 447..496: store straight from registers, no LDS round-trip
        if (tid >= 447 && tid <= 496) {
            float2 r; r.x = pn0[4]; r.y = pn1[4];
            *reinterpret_cast<float2*>(&out[shot * 100000 + t * 100 + (tid2 - 894)]) = r;
        }
        __syncthreads();             // Ps writes visible before next step's reads
    }
}

extern "C" void kernel_launch(void* const* d_in, const int* in_sizes, int n_in,
                              void* d_out, int out_size, void* d_ws, size_t ws_size,
                              hipStream_t stream) {
    const float* v = (const float*)d_in[0];
    float* ws = (float*)d_ws;                       // [0..999] wavelet, [1000..1009] amps, [1010] velmin
    float2* cst = (float2*)((char*)d_ws + 4096);    // 20800 x {alpha, temp1}
    float* out = (float*)d_out;

    fwi_setup1<<<1, 1024, 0, stream>>>(v, ws);
    fwi_setup2<<<82, 256, 0, stream>>>(v, ws, cst);
    fwi_main<<<10, 512, 0, stream>>>((const float4*)cst, ws, out);
}